// Round 1
// baseline (936.720 us; speedup 1.0000x reference)
//
#include <hip/hip_runtime.h>

// Thread-per-row argmax-onehot, v4.
//   - BRANCH-FREE compute: row index clamped (nrows==2M divides the grid
//     exactly, so the clamp never fires in practice); guarantees W/b reads are
//     wave-uniform at top level -> s_load scalar path, no divergent-guard
//     scalarization hazard. Stores remain masked for generality.
//   - PACKED fp32: adjacent output columns packed as float2 and accumulated
//     with __builtin_elementwise_fma -> v_pk_fma_f32 (2 FMA/instr), W pair as
//     one aligned SGPR-pair operand. Halves VALU instruction count. Each
//     column's chain is still strict k-ascending IEEE fmaf + one bias add ->
//     logits bitwise-identical to v3 (verified absmax 0 in prior rounds).
//   - full x row hoisted into 16 float4 VGPRs up-front (one load burst).
//   - coalesced float4 one-hot tile store with __shfl'd argmax (v3 code).

typedef __attribute__((ext_vector_type(2))) float f32x2;
typedef __attribute__((ext_vector_type(4))) float f32x4;

// W column-pair P (columns 2P, 2P+1) of a W row base pointer.
#define W2(WR, P) (*(const f32x2*)((WR) + ((P) << 1)))

#define PK1(C, XKK, WR, P) (C) = __builtin_elementwise_fma((XKK), W2((WR), (P)), (C));

// one k against all 64 columns (32 packed pairs)
#define PK32(XK, WR) {                                                        \
    const f32x2 xkk_ = {(XK), (XK)};                                          \
    PK1(c0,  xkk_, (WR), 0)  PK1(c1,  xkk_, (WR), 1)                          \
    PK1(c2,  xkk_, (WR), 2)  PK1(c3,  xkk_, (WR), 3)                          \
    PK1(c4,  xkk_, (WR), 4)  PK1(c5,  xkk_, (WR), 5)                          \
    PK1(c6,  xkk_, (WR), 6)  PK1(c7,  xkk_, (WR), 7)                          \
    PK1(c8,  xkk_, (WR), 8)  PK1(c9,  xkk_, (WR), 9)                          \
    PK1(c10, xkk_, (WR), 10) PK1(c11, xkk_, (WR), 11)                         \
    PK1(c12, xkk_, (WR), 12) PK1(c13, xkk_, (WR), 13)                         \
    PK1(c14, xkk_, (WR), 14) PK1(c15, xkk_, (WR), 15)                         \
    PK1(c16, xkk_, (WR), 16) PK1(c17, xkk_, (WR), 17)                         \
    PK1(c18, xkk_, (WR), 18) PK1(c19, xkk_, (WR), 19)                         \
    PK1(c20, xkk_, (WR), 20) PK1(c21, xkk_, (WR), 21)                         \
    PK1(c22, xkk_, (WR), 22) PK1(c23, xkk_, (WR), 23)                         \
    PK1(c24, xkk_, (WR), 24) PK1(c25, xkk_, (WR), 25)                         \
    PK1(c26, xkk_, (WR), 26) PK1(c27, xkk_, (WR), 27)                         \
    PK1(c28, xkk_, (WR), 28) PK1(c29, xkk_, (WR), 29)                         \
    PK1(c30, xkk_, (WR), 30) PK1(c31, xkk_, (WR), 31)                         \
}

// one x float4 (4 consecutive k) against W rows at base (W + KK*256)
#define PKBLK(XV, KK)                                                         \
    PK32((XV).x, W + (KK) * 256)                                              \
    PK32((XV).y, W + (KK) * 256 + 64)                                         \
    PK32((XV).z, W + (KK) * 256 + 128)                                        \
    PK32((XV).w, W + (KK) * 256 + 192)

#define ADDB2(C, P) (C) += *(const f32x2*)(bp + ((P) << 1));

#define CHK(V, J)                                                             \
    if ((V) > best) { best = (V); idx = (J); }

#define CHK2(C, P) CHK((C).x, 2 * (P)) CHK((C).y, 2 * (P) + 1)

__global__ __launch_bounds__(256) void onehot_argmax_kernel(
    const float* __restrict__ x, const float* __restrict__ W,
    const float* __restrict__ b, float* __restrict__ out, int nrows)
{
    const int lane = threadIdx.x & 63;
    const int wave = threadIdx.x >> 6;
    const long waveRow0 = (long)blockIdx.x * 256 + (long)wave * 64;
    long r = waveRow0 + lane;
    // branch-free: clamp instead of guarding (stores are masked below).
    if (r >= nrows) r = nrows - 1;

    const f32x2 z2 = {0.f, 0.f};
    f32x2 c0 = z2,  c1 = z2,  c2 = z2,  c3 = z2,  c4 = z2,  c5 = z2,  c6 = z2,  c7 = z2;
    f32x2 c8 = z2,  c9 = z2,  c10 = z2, c11 = z2, c12 = z2, c13 = z2, c14 = z2, c15 = z2;
    f32x2 c16 = z2, c17 = z2, c18 = z2, c19 = z2, c20 = z2, c21 = z2, c22 = z2, c23 = z2;
    f32x2 c24 = z2, c25 = z2, c26 = z2, c27 = z2, c28 = z2, c29 = z2, c30 = z2, c31 = z2;

    const f32x4* __restrict__ xr4 = (const f32x4*)(x + r * 64);
    // hoist the whole row: 16 back-to-back dwordx4 loads, one wait.
    const f32x4 x0 = xr4[0],  x1 = xr4[1],  x2 = xr4[2],  x3 = xr4[3];
    const f32x4 x4 = xr4[4],  x5 = xr4[5],  x6 = xr4[6],  x7 = xr4[7];
    const f32x4 x8 = xr4[8],  x9 = xr4[9],  x10 = xr4[10], x11 = xr4[11];
    const f32x4 x12 = xr4[12], x13 = xr4[13], x14 = xr4[14], x15 = xr4[15];

    PKBLK(x0, 0)   PKBLK(x1, 1)   PKBLK(x2, 2)   PKBLK(x3, 3)
    PKBLK(x4, 4)   PKBLK(x5, 5)   PKBLK(x6, 6)   PKBLK(x7, 7)
    PKBLK(x8, 8)   PKBLK(x9, 9)   PKBLK(x10, 10) PKBLK(x11, 11)
    PKBLK(x12, 12) PKBLK(x13, 13) PKBLK(x14, 14) PKBLK(x15, 15)

    // bias (single packed add per column pair, same per-column order as ref)
    const float* __restrict__ bp = b;
    ADDB2(c0, 0)   ADDB2(c1, 1)   ADDB2(c2, 2)   ADDB2(c3, 3)
    ADDB2(c4, 4)   ADDB2(c5, 5)   ADDB2(c6, 6)   ADDB2(c7, 7)
    ADDB2(c8, 8)   ADDB2(c9, 9)   ADDB2(c10, 10) ADDB2(c11, 11)
    ADDB2(c12, 12) ADDB2(c13, 13) ADDB2(c14, 14) ADDB2(c15, 15)
    ADDB2(c16, 16) ADDB2(c17, 17) ADDB2(c18, 18) ADDB2(c19, 19)
    ADDB2(c20, 20) ADDB2(c21, 21) ADDB2(c22, 22) ADDB2(c23, 23)
    ADDB2(c24, 24) ADDB2(c25, 25) ADDB2(c26, 26) ADDB2(c27, 27)
    ADDB2(c28, 28) ADDB2(c29, 29) ADDB2(c30, 30) ADDB2(c31, 31)

    // first-index argmax (strict >) — matches numpy tie-break
    float best = c0.x;
    int idx = 0;
    CHK(c0.y, 1)
    CHK2(c1, 1)   CHK2(c2, 2)   CHK2(c3, 3)   CHK2(c4, 4)
    CHK2(c5, 5)   CHK2(c6, 6)   CHK2(c7, 7)   CHK2(c8, 8)
    CHK2(c9, 9)   CHK2(c10, 10) CHK2(c11, 11) CHK2(c12, 12)
    CHK2(c13, 13) CHK2(c14, 14) CHK2(c15, 15) CHK2(c16, 16)
    CHK2(c17, 17) CHK2(c18, 18) CHK2(c19, 19) CHK2(c20, 20)
    CHK2(c21, 21) CHK2(c22, 22) CHK2(c23, 23) CHK2(c24, 24)
    CHK2(c25, 25) CHK2(c26, 26) CHK2(c27, 27) CHK2(c28, 28)
    CHK2(c29, 29) CHK2(c30, 30) CHK2(c31, 31)

    // Coalesced one-hot write: wave fills its 64-row tile (1024 float4s).
    // float4 #f of the tile belongs to row (f>>4), columns 4*(f&15)..+3.
    float4* __restrict__ outw = (float4*)(out + waveRow0 * 64);
    const long remf4 = ((long)nrows - waveRow0) * 16;  // float4s valid in tile
#pragma unroll
    for (int i = 0; i < 16; ++i) {
        const int f = i * 64 + lane;
        const int idx_r = __shfl(idx, f >> 4, 64);  // argmax of the row this f belongs to
        const bool m = ((idx_r >> 2) == (f & 15));
        const int c = idx_r & 3;
        float4 v;
        v.x = (m && c == 0) ? 1.0f : 0.0f;
        v.y = (m && c == 1) ? 1.0f : 0.0f;
        v.z = (m && c == 2) ? 1.0f : 0.0f;
        v.w = (m && c == 3) ? 1.0f : 0.0f;
        if (f < remf4) outw[f] = v;
    }
}

extern "C" void kernel_launch(void* const* d_in, const int* in_sizes, int n_in,
                              void* d_out, int out_size, void* d_ws, size_t ws_size,
                              hipStream_t stream) {
    const float* x = (const float*)d_in[0];
    const float* W = (const float*)d_in[1];
    const float* b = (const float*)d_in[2];
    float* out = (float*)d_out;

    const int nrows = in_sizes[0] / 64;
    dim3 block(256);
    dim3 grid((nrows + 255) / 256);  // 8192 blocks at B=2M
    hipLaunchKernelGGL(onehot_argmax_kernel, grid, block, 0, stream,
                       x, W, b, out, nrows);
}

// Round 2
// 934.733 us; speedup vs baseline: 1.0021x; 1.0021x over previous
//
#include <hip/hip_runtime.h>

// Thread-per-row argmax-onehot, v5.
//   - COALESCED x via LDS staging: each wave stages its 64-row x 256B tile
//     with 16 global_load_lds dwordx4 (wave-wide 1 KiB contiguous per instr,
//     async, no VGPR round-trip). v4's per-lane 256B-stride loads made every
//     load instr touch 64 distinct lines (~1024 VMEM transactions/wave + L1
//     thrash) -> kernel ran 3.2 TB/s vs 6.2 TB/s fill-proven ceiling.
//   - LDS layout: linear dest (global_load_lds requirement) + PRE-SWIZZLED
//     global source (m173 pattern). Swizzle idx = (row<<4)|(q ^ (row&7)) is an
//     involution within each row's 16 float4s and stays inside 128B segments
//     -> global coalescing intact, per-row ds_read_b128 readback hits all 32
//     banks per 8 lanes (floor rate, no conflict).
//   - compute tail identical to v4: packed f32x2 FMA chains, strict
//     k-ascending per column + single bias add -> logits bitwise-identical
//     (absmax 0.0 verified), strict-> first-index argmax, coalesced float4
//     one-hot tile store with __shfl'd argmax.

typedef __attribute__((ext_vector_type(2))) float f32x2;
typedef __attribute__((ext_vector_type(4))) float f32x4;

// W column-pair P (columns 2P, 2P+1) of a W row base pointer.
#define W2(WR, P) (*(const f32x2*)((WR) + ((P) << 1)))

#define PK1(C, XKK, WR, P) (C) = __builtin_elementwise_fma((XKK), W2((WR), (P)), (C));

// one k against all 64 columns (32 packed pairs)
#define PK32(XK, WR) {                                                        \
    const f32x2 xkk_ = {(XK), (XK)};                                          \
    PK1(c0,  xkk_, (WR), 0)  PK1(c1,  xkk_, (WR), 1)                          \
    PK1(c2,  xkk_, (WR), 2)  PK1(c3,  xkk_, (WR), 3)                          \
    PK1(c4,  xkk_, (WR), 4)  PK1(c5,  xkk_, (WR), 5)                          \
    PK1(c6,  xkk_, (WR), 6)  PK1(c7,  xkk_, (WR), 7)                          \
    PK1(c8,  xkk_, (WR), 8)  PK1(c9,  xkk_, (WR), 9)                          \
    PK1(c10, xkk_, (WR), 10) PK1(c11, xkk_, (WR), 11)                         \
    PK1(c12, xkk_, (WR), 12) PK1(c13, xkk_, (WR), 13)                         \
    PK1(c14, xkk_, (WR), 14) PK1(c15, xkk_, (WR), 15)                         \
    PK1(c16, xkk_, (WR), 16) PK1(c17, xkk_, (WR), 17)                         \
    PK1(c18, xkk_, (WR), 18) PK1(c19, xkk_, (WR), 19)                         \
    PK1(c20, xkk_, (WR), 20) PK1(c21, xkk_, (WR), 21)                         \
    PK1(c22, xkk_, (WR), 22) PK1(c23, xkk_, (WR), 23)                         \
    PK1(c24, xkk_, (WR), 24) PK1(c25, xkk_, (WR), 25)                         \
    PK1(c26, xkk_, (WR), 26) PK1(c27, xkk_, (WR), 27)                         \
    PK1(c28, xkk_, (WR), 28) PK1(c29, xkk_, (WR), 29)                         \
    PK1(c30, xkk_, (WR), 30) PK1(c31, xkk_, (WR), 31)                         \
}

// one x float4 (4 consecutive k) against W rows at base (W + KK*256)
#define PKBLK(XV, KK)                                                         \
    PK32((XV).x, W + (KK) * 256)                                              \
    PK32((XV).y, W + (KK) * 256 + 64)                                         \
    PK32((XV).z, W + (KK) * 256 + 128)                                        \
    PK32((XV).w, W + (KK) * 256 + 192)

#define ADDB2(C, P) (C) += *(const f32x2*)(bp + ((P) << 1));

#define CHK(V, J)                                                             \
    if ((V) > best) { best = (V); idx = (J); }

#define CHK2(C, P) CHK((C).x, 2 * (P)) CHK((C).y, 2 * (P) + 1)

// swizzled source float4 for linear LDS slot I (involution, row-preserving)
#define SWZ_SRC(I) (((I) & ~15) | (((I) & 15) ^ (((I) >> 4) & 7)))

__global__ __launch_bounds__(256, 2) void onehot_argmax_kernel(
    const float* __restrict__ x, const float* __restrict__ W,
    const float* __restrict__ b, float* __restrict__ out, int nrows)
{
    const int lane = threadIdx.x & 63;
    const int wave = threadIdx.x >> 6;
    const long waveRow0 = (long)blockIdx.x * 256 + (long)wave * 64;

    __shared__ f32x4 sbuf[4][1024];          // 16 KiB per wave, wave-private
    f32x4* __restrict__ wbuf = &sbuf[wave][0];

    const float* __restrict__ tile = x + waveRow0 * 64;   // this wave's x tile
    const long remf4 = ((long)nrows - waveRow0) * 16;     // valid float4s in tile

    // ---- coalesced async staging: global -> LDS (linear dest, swizzled src)
    if (remf4 >= 1024) {
#pragma unroll
        for (int t = 0; t < 16; ++t) {
            const int I = t * 64 + lane;
            const int f = SWZ_SRC(I);
            __builtin_amdgcn_global_load_lds(
                (const __attribute__((address_space(1))) void*)(tile + (long)f * 4),
                (__attribute__((address_space(3))) void*)(wbuf + t * 64),
                16, 0, 0);
        }
    } else {
#pragma unroll
        for (int t = 0; t < 16; ++t) {
            const int I = t * 64 + lane;
            const int f = SWZ_SRC(I);
            if (f < remf4) {
                __builtin_amdgcn_global_load_lds(
                    (const __attribute__((address_space(1))) void*)(tile + (long)f * 4),
                    (__attribute__((address_space(3))) void*)(wbuf + t * 64),
                    16, 0, 0);
            }
        }
    }
    asm volatile("s_waitcnt vmcnt(0)" ::: "memory");

    // ---- swizzled per-row readback: lane's row = lane, bank-conflict-free
    const int swz = lane & 7;
    const int rb = lane << 4;
#define LDX(Q) wbuf[rb | ((Q) ^ swz)]
    const f32x4 x0 = LDX(0),  x1 = LDX(1),  x2 = LDX(2),  x3 = LDX(3);
    const f32x4 x4 = LDX(4),  x5 = LDX(5),  x6 = LDX(6),  x7 = LDX(7);
    const f32x4 x8 = LDX(8),  x9 = LDX(9),  x10 = LDX(10), x11 = LDX(11);
    const f32x4 x12 = LDX(12), x13 = LDX(13), x14 = LDX(14), x15 = LDX(15);

    const f32x2 z2 = {0.f, 0.f};
    f32x2 c0 = z2,  c1 = z2,  c2 = z2,  c3 = z2,  c4 = z2,  c5 = z2,  c6 = z2,  c7 = z2;
    f32x2 c8 = z2,  c9 = z2,  c10 = z2, c11 = z2, c12 = z2, c13 = z2, c14 = z2, c15 = z2;
    f32x2 c16 = z2, c17 = z2, c18 = z2, c19 = z2, c20 = z2, c21 = z2, c22 = z2, c23 = z2;
    f32x2 c24 = z2, c25 = z2, c26 = z2, c27 = z2, c28 = z2, c29 = z2, c30 = z2, c31 = z2;

    PKBLK(x0, 0)   PKBLK(x1, 1)   PKBLK(x2, 2)   PKBLK(x3, 3)
    PKBLK(x4, 4)   PKBLK(x5, 5)   PKBLK(x6, 6)   PKBLK(x7, 7)
    PKBLK(x8, 8)   PKBLK(x9, 9)   PKBLK(x10, 10) PKBLK(x11, 11)
    PKBLK(x12, 12) PKBLK(x13, 13) PKBLK(x14, 14) PKBLK(x15, 15)

    // bias (single packed add per column pair, same per-column order as ref)
    const float* __restrict__ bp = b;
    ADDB2(c0, 0)   ADDB2(c1, 1)   ADDB2(c2, 2)   ADDB2(c3, 3)
    ADDB2(c4, 4)   ADDB2(c5, 5)   ADDB2(c6, 6)   ADDB2(c7, 7)
    ADDB2(c8, 8)   ADDB2(c9, 9)   ADDB2(c10, 10) ADDB2(c11, 11)
    ADDB2(c12, 12) ADDB2(c13, 13) ADDB2(c14, 14) ADDB2(c15, 15)
    ADDB2(c16, 16) ADDB2(c17, 17) ADDB2(c18, 18) ADDB2(c19, 19)
    ADDB2(c20, 20) ADDB2(c21, 21) ADDB2(c22, 22) ADDB2(c23, 23)
    ADDB2(c24, 24) ADDB2(c25, 25) ADDB2(c26, 26) ADDB2(c27, 27)
    ADDB2(c28, 28) ADDB2(c29, 29) ADDB2(c30, 30) ADDB2(c31, 31)

    // first-index argmax (strict >) — matches numpy tie-break
    float best = c0.x;
    int idx = 0;
    CHK(c0.y, 1)
    CHK2(c1, 1)   CHK2(c2, 2)   CHK2(c3, 3)   CHK2(c4, 4)
    CHK2(c5, 5)   CHK2(c6, 6)   CHK2(c7, 7)   CHK2(c8, 8)
    CHK2(c9, 9)   CHK2(c10, 10) CHK2(c11, 11) CHK2(c12, 12)
    CHK2(c13, 13) CHK2(c14, 14) CHK2(c15, 15) CHK2(c16, 16)
    CHK2(c17, 17) CHK2(c18, 18) CHK2(c19, 19) CHK2(c20, 20)
    CHK2(c21, 21) CHK2(c22, 22) CHK2(c23, 23) CHK2(c24, 24)
    CHK2(c25, 25) CHK2(c26, 26) CHK2(c27, 27) CHK2(c28, 28)
    CHK2(c29, 29) CHK2(c30, 30) CHK2(c31, 31)

    // Coalesced one-hot write: wave fills its 64-row tile (1024 float4s).
    // float4 #f of the tile belongs to row (f>>4), columns 4*(f&15)..+3.
    float4* __restrict__ outw = (float4*)(out + waveRow0 * 64);
#pragma unroll
    for (int i = 0; i < 16; ++i) {
        const int f = i * 64 + lane;
        const int idx_r = __shfl(idx, f >> 4, 64);  // argmax of the row this f belongs to
        const bool m = ((idx_r >> 2) == (f & 15));
        const int c = idx_r & 3;
        float4 v;
        v.x = (m && c == 0) ? 1.0f : 0.0f;
        v.y = (m && c == 1) ? 1.0f : 0.0f;
        v.z = (m && c == 2) ? 1.0f : 0.0f;
        v.w = (m && c == 3) ? 1.0f : 0.0f;
        if (f < remf4) outw[f] = v;
    }
}

extern "C" void kernel_launch(void* const* d_in, const int* in_sizes, int n_in,
                              void* d_out, int out_size, void* d_ws, size_t ws_size,
                              hipStream_t stream) {
    const float* x = (const float*)d_in[0];
    const float* W = (const float*)d_in[1];
    const float* b = (const float*)d_in[2];
    float* out = (float*)d_out;

    const int nrows = in_sizes[0] / 64;
    dim3 block(256);
    dim3 grid((nrows + 255) / 256);  // 8192 blocks at B=2M
    hipLaunchKernelGGL(onehot_argmax_kernel, grid, block, 0, stream,
                       x, W, b, out, nrows);
}